// Round 1
// baseline (1650.450 us; speedup 1.0000x reference)
//
#include <hip/hip_runtime.h>
#include <math.h>

static constexpr int N   = 3072;
static constexpr int DIN = 64;
static constexpr int D   = 128;
static constexpr int H   = 4;
static constexpr int E   = 49152;
#define NEGV  (-4294967295.0f)
#define SCALE (0.08838834764831845f)   // 1/sqrt(128)

// ---------------------------------------------------------------- deg / h0
__global__ void k_zero_deg(int* __restrict__ deg){
  int i = blockIdx.x*blockDim.x + threadIdx.x;
  if(i < N) deg[i] = 0;
}

__global__ void k_deg(const int* __restrict__ ei, int* __restrict__ deg){
  int e = blockIdx.x*blockDim.x + threadIdx.x;
  if(e < E) atomicAdd(&deg[ei[E + e]], 1);
}

// block = 64 threads (1 wave), one row per block
__global__ void k_h0(const float* __restrict__ x, const float* __restrict__ nodeW,
                     const float* __restrict__ nodeb, const float* __restrict__ degemb,
                     const int* __restrict__ deg, float* __restrict__ mask,
                     float* __restrict__ h){
  const int i = blockIdx.x, t = threadIdx.x;
  float xv = x[i*DIN + t];
  float s = xv;
  #pragma unroll
  for(int o=32;o;o>>=1) s += __shfl_xor(s, o);
  if(t == 0) mask[i] = (s != 0.0f) ? 1.0f : 0.0f;
  __shared__ float xr[DIN];
  xr[t] = xv;
  __syncthreads();
  int dg = deg[i]; dg = dg > N-1 ? N-1 : dg;
  float a0 = nodeb[t]      + degemb[dg*D + t];
  float a1 = nodeb[t + 64] + degemb[dg*D + t + 64];
  #pragma unroll
  for(int u=0; u<DIN; ++u){
    float xu = xr[u];
    a0 = fmaf(xu, nodeW[u*D + t],      a0);
    a1 = fmaf(xu, nodeW[u*D + t + 64], a1);
  }
  h[i*D + t]      = a0;
  h[i*D + t + 64] = a1;
}

// ---------------------------------------------------------------- bias (masked)
// bias[i,j] = sp_emb[spl[i,j]] + ef[i,j,:].row_mean(edge_W) + mean(edge_b); NEG if masked
__global__ void k_bias(const int* __restrict__ spl, const float* __restrict__ ef,
                       const float* __restrict__ spe, const float* __restrict__ eW,
                       const float* __restrict__ eb, const float* __restrict__ mask,
                       float* __restrict__ biasm){
  int idx = blockIdx.x*blockDim.x + threadIdx.x;   // < N*N (9.4M, fits int)
  int i = idx / N, j = idx % N;
  float wm0 = (eW[0] + eW[1] + eW[2] + eW[3])  * 0.25f;
  float wm1 = (eW[4] + eW[5] + eW[6] + eW[7])  * 0.25f;
  float wm2 = (eW[8] + eW[9] + eW[10]+ eW[11]) * 0.25f;
  float wm3 = (eW[12]+ eW[13]+ eW[14]+ eW[15]) * 0.25f;
  float bm  = (eb[0] + eb[1] + eb[2] + eb[3])  * 0.25f;
  float4 e4 = reinterpret_cast<const float4*>(ef)[idx];
  float em = fmaf(e4.x, wm0, fmaf(e4.y, wm1, fmaf(e4.z, wm2, fmaf(e4.w, wm3, bm))));
  float b = spe[spl[idx]] + em;
  float mk = mask[i]*mask[j];
  biasm[idx] = (mk != 0.0f) ? b : NEGV;
}

// ---------------------------------------------------------------- layernorm
// block 256 = 4 waves, one row per wave, 2 elems per lane
__global__ void k_ln(const float* __restrict__ in, const float* __restrict__ g,
                     const float* __restrict__ b, float* __restrict__ out){
  const int w = threadIdx.x >> 6, lane = threadIdx.x & 63;
  const int row = blockIdx.x*4 + w;
  const float* r = in + row*D;
  float v0 = r[lane], v1 = r[lane + 64];
  float s = v0 + v1, sq = v0*v0 + v1*v1;
  #pragma unroll
  for(int o=32;o;o>>=1){ s += __shfl_xor(s, o); sq += __shfl_xor(sq, o); }
  float mean = s*(1.0f/128.0f);
  float var  = sq*(1.0f/128.0f) - mean*mean;
  float inv  = rsqrtf(var + 1e-5f);
  out[row*D + lane]      = (v0 - mean)*inv*g[lane]      + b[lane];
  out[row*D + lane + 64] = (v1 - mean)*inv*g[lane + 64] + b[lane + 64];
}

// ---------------------------------------------------------------- fp32 SGEMM 64x64 tile
// C[M,Nc] = A[M,K] @ B[K,Nc] + bias[Nc] (+ res[M,Nc]); all dims multiples of tile
template<bool RES>
__device__ __forceinline__ void gemm_body(const float* __restrict__ A, const float* __restrict__ B,
                                          const float* __restrict__ bias, const float* __restrict__ res,
                                          float* __restrict__ C, int M, int Nc, int K){
  __shared__ float As[16][72];   // [k][m], padded rows (288B) for aligned float4 reads
  __shared__ float Bs[16][72];   // [k][n]
  const int tid  = threadIdx.x;
  const int m0   = blockIdx.x*64, n0 = blockIdx.y*64;
  const int tx   = tid & 15, ty = tid >> 4;
  const int arow = tid >> 2, akq = tid & 3;
  const int brow = tid >> 4, bnq = tid & 15;
  float acc[4][4] = {};
  for(int k0 = 0; k0 < K; k0 += 16){
    __syncthreads();
    float4 av = *reinterpret_cast<const float4*>(A + (m0 + arow)*K + k0 + akq*4);
    As[akq*4+0][arow] = av.x; As[akq*4+1][arow] = av.y;
    As[akq*4+2][arow] = av.z; As[akq*4+3][arow] = av.w;
    float4 bv = *reinterpret_cast<const float4*>(B + (k0 + brow)*Nc + n0 + bnq*4);
    *reinterpret_cast<float4*>(&Bs[brow][bnq*4]) = bv;
    __syncthreads();
    #pragma unroll
    for(int kk = 0; kk < 16; ++kk){
      float4 a4 = *reinterpret_cast<const float4*>(&As[kk][ty*4]);
      float4 b4 = *reinterpret_cast<const float4*>(&Bs[kk][tx*4]);
      float a_[4] = {a4.x, a4.y, a4.z, a4.w};
      float b_[4] = {b4.x, b4.y, b4.z, b4.w};
      #pragma unroll
      for(int i=0;i<4;i++)
        #pragma unroll
        for(int j=0;j<4;j++)
          acc[i][j] = fmaf(a_[i], b_[j], acc[i][j]);
    }
  }
  #pragma unroll
  for(int i=0;i<4;i++){
    int r = m0 + ty*4 + i;
    int c = n0 + tx*4;
    float4 bi = *reinterpret_cast<const float4*>(bias + c);
    float4 o;
    o.x = acc[i][0] + bi.x; o.y = acc[i][1] + bi.y;
    o.z = acc[i][2] + bi.z; o.w = acc[i][3] + bi.w;
    if(RES){
      float4 rv = *reinterpret_cast<const float4*>(res + r*Nc + c);
      o.x += rv.x; o.y += rv.y; o.z += rv.z; o.w += rv.w;
    }
    *reinterpret_cast<float4*>(C + r*Nc + c) = o;
  }
}

template<bool RES>
__global__ __launch_bounds__(256) void k_gemm(const float* __restrict__ A, const float* __restrict__ B,
                                              const float* __restrict__ bias, const float* __restrict__ res,
                                              float* __restrict__ C, int M, int Nc, int K){
  gemm_body<RES>(A, B, bias, res, C, M, Nc, K);
}

// grid.z = which*4 + head (which: 0=q 1=k 2=v)
__global__ __launch_bounds__(256) void k_qkv(const float* __restrict__ xln,
    const float* __restrict__ Wq, const float* __restrict__ Wk, const float* __restrict__ Wv,
    const float* __restrict__ bq, const float* __restrict__ bk, const float* __restrict__ bv,
    float* __restrict__ q, float* __restrict__ k, float* __restrict__ v, int l){
  const int z = blockIdx.z, which = z >> 2, head = z & 3;
  const float* W; const float* bb; float* out;
  if(which == 0){ W = Wq; bb = bq; out = q; }
  else if(which == 1){ W = Wk; bb = bk; out = k; }
  else { W = Wv; bb = bv; out = v; }
  W  += (l*H + head)*D*D;
  bb += (l*H + head)*D;
  out += head*(N*D);
  gemm_body<false>(xln, W, bb, nullptr, out, N, D, D);
}

// ---------------------------------------------------------------- flash attention (fp32)
// block 256; QB=16 query rows, JB=32 key tiles; thread (qi,g): qi=tid/16 row, g=tid%16
// each thread: scores for j = 2g, 2g+1; output slice d = g*8..g*8+7
__global__ __launch_bounds__(256) void k_attn(const float* __restrict__ qg, const float* __restrict__ kg,
                       const float* __restrict__ vg, const float* __restrict__ biasm,
                       const float* __restrict__ mask, float* __restrict__ ocat){
  const int head = blockIdx.y;
  const int r0   = blockIdx.x*16;
  const int tid  = threadIdx.x;
  const int qi   = tid >> 4, g = tid & 15;
  __shared__ float qs[16][132];
  __shared__ float ks[32][132];
  __shared__ float vs[32][132];
  __shared__ float ps[16][33];
  const float* qbase = qg + (size_t)(head*N + r0)*D;
  for(int u = tid; u < 16*32; u += 256){
    int r = u >> 5, c = (u & 31) << 2;
    float4 t = *reinterpret_cast<const float4*>(qbase + r*D + c);
    qs[r][c] = t.x*SCALE; qs[r][c+1] = t.y*SCALE; qs[r][c+2] = t.z*SCALE; qs[r][c+3] = t.w*SCALE;
  }
  float oa[8] = {0,0,0,0,0,0,0,0};
  float m = -INFINITY, lsum = 0.0f;
  const int j0 = 2*g, j1 = 2*g + 1;
  for(int jt = 0; jt < N/32; ++jt){
    __syncthreads();     // prev tile's PV reads done before overwrite (covers q load too)
    const float* kbase = kg + (size_t)(head*N + jt*32)*D;
    const float* vbase = vg + (size_t)(head*N + jt*32)*D;
    for(int u = tid; u < 32*32; u += 256){
      int r = u >> 5, c = (u & 31) << 2;
      float4 t  = *reinterpret_cast<const float4*>(kbase + r*D + c);
      ks[r][c] = t.x;  ks[r][c+1] = t.y;  ks[r][c+2] = t.z;  ks[r][c+3] = t.w;
      float4 t2 = *reinterpret_cast<const float4*>(vbase + r*D + c);
      vs[r][c] = t2.x; vs[r][c+1] = t2.y; vs[r][c+2] = t2.z; vs[r][c+3] = t2.w;
    }
    __syncthreads();
    float acc0 = 0.0f, acc1 = 0.0f;
    #pragma unroll
    for(int t4 = 0; t4 < 32; ++t4){
      float4 qv  = *reinterpret_cast<const float4*>(&qs[qi][t4*4]);
      float4 k0v = *reinterpret_cast<const float4*>(&ks[j0][t4*4]);
      float4 k1v = *reinterpret_cast<const float4*>(&ks[j1][t4*4]);
      acc0 = fmaf(qv.x,k0v.x, fmaf(qv.y,k0v.y, fmaf(qv.z,k0v.z, fmaf(qv.w,k0v.w, acc0))));
      acc1 = fmaf(qv.x,k1v.x, fmaf(qv.y,k1v.y, fmaf(qv.z,k1v.z, fmaf(qv.w,k1v.w, acc1))));
    }
    const float* brow = biasm + (size_t)(r0 + qi)*N + jt*32;
    float s0 = acc0 + brow[j0];
    float s1 = acc1 + brow[j1];
    // row reduce across the 16 lanes holding this row (contiguous lane group)
    float lm = fmaxf(s0, s1);
    #pragma unroll
    for(int o=8;o;o>>=1) lm = fmaxf(lm, __shfl_xor(lm, o));
    float mnew = fmaxf(m, lm);
    float p0 = __expf(s0 - mnew), p1 = __expf(s1 - mnew);
    float corr = __expf(m - mnew);         // m=-inf first iter -> 0, oa already 0
    float psum = p0 + p1;
    #pragma unroll
    for(int o=8;o;o>>=1) psum += __shfl_xor(psum, o);
    lsum = lsum*corr + psum;
    m = mnew;
    #pragma unroll
    for(int u=0;u<8;u++) oa[u] *= corr;
    ps[qi][j0] = p0; ps[qi][j1] = p1;
    __syncthreads();
    #pragma unroll 8
    for(int j=0;j<32;j++){
      float pj = ps[qi][j];
      float4 va = *reinterpret_cast<const float4*>(&vs[j][g*8]);
      float4 vb = *reinterpret_cast<const float4*>(&vs[j][g*8+4]);
      oa[0] = fmaf(pj, va.x, oa[0]); oa[1] = fmaf(pj, va.y, oa[1]);
      oa[2] = fmaf(pj, va.z, oa[2]); oa[3] = fmaf(pj, va.w, oa[3]);
      oa[4] = fmaf(pj, vb.x, oa[4]); oa[5] = fmaf(pj, vb.y, oa[5]);
      oa[6] = fmaf(pj, vb.z, oa[6]); oa[7] = fmaf(pj, vb.w, oa[7]);
    }
  }
  float mk  = mask[r0 + qi];               // zero out fully-masked rows (post-softmax re-mask)
  float inv = (lsum > 0.0f) ? mk/lsum : 0.0f;
  float* orow = ocat + (size_t)(r0 + qi)*(H*D) + head*D + g*8;
  float4 o1 = make_float4(oa[0]*inv, oa[1]*inv, oa[2]*inv, oa[3]*inv);
  float4 o2 = make_float4(oa[4]*inv, oa[5]*inv, oa[6]*inv, oa[7]*inv);
  *reinterpret_cast<float4*>(orow)     = o1;
  *reinterpret_cast<float4*>(orow + 4) = o2;
}

// ---------------------------------------------------------------- launch
extern "C" void kernel_launch(void* const* d_in, const int* in_sizes, int n_in,
                              void* d_out, int out_size, void* d_ws, size_t ws_size,
                              hipStream_t stream){
  const float* x      = (const float*)d_in[0];
  const int*   ei     = (const int*)  d_in[1];
  const int*   spl    = (const int*)  d_in[2];
  const float* ef     = (const float*)d_in[3];
  const float* nodeW  = (const float*)d_in[4];
  const float* nodeb  = (const float*)d_in[5];
  const float* degemb = (const float*)d_in[6];
  const float* spe    = (const float*)d_in[7];
  const float* eW     = (const float*)d_in[8];
  const float* eb     = (const float*)d_in[9];
  const float* ln1g   = (const float*)d_in[10];
  const float* ln1b   = (const float*)d_in[11];
  const float* Wq     = (const float*)d_in[12];
  const float* bq     = (const float*)d_in[13];
  const float* Wk     = (const float*)d_in[14];
  const float* bk     = (const float*)d_in[15];
  const float* Wv     = (const float*)d_in[16];
  const float* bv     = (const float*)d_in[17];
  const float* Wo     = (const float*)d_in[18];
  const float* bo     = (const float*)d_in[19];
  const float* ln2g   = (const float*)d_in[20];
  const float* ln2b   = (const float*)d_in[21];
  const float* ffW    = (const float*)d_in[22];
  const float* ffb    = (const float*)d_in[23];
  const float* outW   = (const float*)d_in[24];
  const float* outb   = (const float*)d_in[25];

  float* ws   = (float*)d_ws;
  int*   deg  = (int*)ws;                 // N ints (padded region 4096 floats)
  float* mask = ws + 4096;                // N
  float* h    = ws + 8192;                // N*D
  float* xln  = h    + N*D;
  float* xout = xln  + N*D;
  float* qb   = xout + N*D;               // H*N*D each
  float* kb   = qb   + H*N*D;
  float* vb   = kb   + H*N*D;
  float* ocat = vb   + H*N*D;             // [N, H*D]
  float* biasm= ocat + N*H*D;             // N*N
  // total: 8192 + 3*N*D + 4*H*N*D + N*N floats ≈ 67.7 MB

  k_zero_deg<<<(N+255)/256, 256, 0, stream>>>(deg);
  k_deg<<<(E+255)/256, 256, 0, stream>>>(ei, deg);
  k_h0<<<N, 64, 0, stream>>>(x, nodeW, nodeb, degemb, deg, mask, h);
  k_bias<<<(N*N)/256, 256, 0, stream>>>(spl, ef, spe, eW, eb, mask, biasm);

  for(int l = 0; l < 2; ++l){
    k_ln<<<N/4, 256, 0, stream>>>(h, ln1g + l*D, ln1b + l*D, xln);
    k_qkv<<<dim3(N/64, D/64, 12), 256, 0, stream>>>(xln, Wq, Wk, Wv, bq, bk, bv, qb, kb, vb, l);
    k_attn<<<dim3(N/16, H), 256, 0, stream>>>(qb, kb, vb, biasm, mask, ocat);
    k_gemm<true><<<dim3(N/64, D/64), 256, 0, stream>>>(ocat, Wo + l*(H*D*D), bo + l*D, h, xout, N, D, H*D);
    k_ln<<<N/4, 256, 0, stream>>>(xout, ln2g + l*D, ln2b + l*D, xln);
    k_gemm<true><<<dim3(N/64, D/64), 256, 0, stream>>>(xln, ffW + l*D*D, ffb + l*D, xout, h, N, D, D);
  }
  k_gemm<false><<<dim3(N/64, D/64), 256, 0, stream>>>(h, outW, outb, nullptr, (float*)d_out, N, D, D);
}

// Round 2
// 505.715 us; speedup vs baseline: 3.2636x; 3.2636x over previous
//
#include <hip/hip_runtime.h>
#include <math.h>

static constexpr int N   = 3072;
static constexpr int DIN = 64;
static constexpr int D   = 128;
static constexpr int H   = 4;
static constexpr int E   = 49152;
static constexpr int SPLIT = 2;
#define NEGV  (-4294967295.0f)
#define SCALE (0.08838834764831845f)   // 1/sqrt(128)

typedef unsigned short u16;
typedef __attribute__((ext_vector_type(8))) short short8;
typedef __attribute__((ext_vector_type(4))) float f32x4;
typedef __attribute__((ext_vector_type(4))) unsigned short u16x4;

__device__ __forceinline__ u16 f2bf(float f){           // RNE float->bf16
  unsigned int u = __float_as_uint(f);
  u += 0x7fff + ((u >> 16) & 1);
  return (u16)(u >> 16);
}
__device__ __forceinline__ float bf2f(u16 u){
  return __uint_as_float(((unsigned int)u) << 16);
}

// ---------------------------------------------------------------- deg / h0
__global__ void k_zero_deg(int* __restrict__ deg){
  int i = blockIdx.x*blockDim.x + threadIdx.x;
  if(i < N) deg[i] = 0;
}

__global__ void k_deg(const int* __restrict__ ei, int* __restrict__ deg){
  int e = blockIdx.x*blockDim.x + threadIdx.x;
  if(e < E) atomicAdd(&deg[ei[E + e]], 1);
}

__global__ void k_h0(const float* __restrict__ x, const float* __restrict__ nodeW,
                     const float* __restrict__ nodeb, const float* __restrict__ degemb,
                     const int* __restrict__ deg, float* __restrict__ mask,
                     float* __restrict__ h){
  const int i = blockIdx.x, t = threadIdx.x;
  float xv = x[i*DIN + t];
  float s = xv;
  #pragma unroll
  for(int o=32;o;o>>=1) s += __shfl_xor(s, o);
  if(t == 0) mask[i] = (s != 0.0f) ? 1.0f : 0.0f;
  __shared__ float xr[DIN];
  xr[t] = xv;
  __syncthreads();
  int dg = deg[i]; dg = dg > N-1 ? N-1 : dg;
  float a0 = nodeb[t]      + degemb[dg*D + t];
  float a1 = nodeb[t + 64] + degemb[dg*D + t + 64];
  #pragma unroll
  for(int u=0; u<DIN; ++u){
    float xu = xr[u];
    a0 = fmaf(xu, nodeW[u*D + t],      a0);
    a1 = fmaf(xu, nodeW[u*D + t + 64], a1);
  }
  h[i*D + t]      = a0;
  h[i*D + t + 64] = a1;
}

// ---------------------------------------------------------------- bias (masked, bf16)
__global__ void k_bias(const int* __restrict__ spl, const float* __restrict__ ef,
                       const float* __restrict__ spe, const float* __restrict__ eW,
                       const float* __restrict__ eb, const float* __restrict__ mask,
                       u16* __restrict__ biasm){
  int idx = blockIdx.x*blockDim.x + threadIdx.x;   // < N*N
  int i = idx / N, j = idx % N;
  float wm0 = (eW[0] + eW[1] + eW[2] + eW[3])  * 0.25f;
  float wm1 = (eW[4] + eW[5] + eW[6] + eW[7])  * 0.25f;
  float wm2 = (eW[8] + eW[9] + eW[10]+ eW[11]) * 0.25f;
  float wm3 = (eW[12]+ eW[13]+ eW[14]+ eW[15]) * 0.25f;
  float bm  = (eb[0] + eb[1] + eb[2] + eb[3])  * 0.25f;
  float4 e4 = reinterpret_cast<const float4*>(ef)[idx];
  float em = fmaf(e4.x, wm0, fmaf(e4.y, wm1, fmaf(e4.z, wm2, fmaf(e4.w, wm3, bm))));
  float b = spe[spl[idx]] + em;
  float mk = mask[i]*mask[j];
  biasm[idx] = f2bf((mk != 0.0f) ? b : NEGV);
}

// ---------------------------------------------------------------- layernorm
__global__ void k_ln(const float* __restrict__ in, const float* __restrict__ g,
                     const float* __restrict__ b, float* __restrict__ out){
  const int w = threadIdx.x >> 6, lane = threadIdx.x & 63;
  const int row = blockIdx.x*4 + w;
  const float* r = in + row*D;
  float v0 = r[lane], v1 = r[lane + 64];
  float s = v0 + v1, sq = v0*v0 + v1*v1;
  #pragma unroll
  for(int o=32;o;o>>=1){ s += __shfl_xor(s, o); sq += __shfl_xor(sq, o); }
  float mean = s*(1.0f/128.0f);
  float var  = sq*(1.0f/128.0f) - mean*mean;
  float inv  = rsqrtf(var + 1e-5f);
  out[row*D + lane]      = (v0 - mean)*inv*g[lane]      + b[lane];
  out[row*D + lane + 64] = (v1 - mean)*inv*g[lane + 64] + b[lane + 64];
}

// ---------------------------------------------------------------- fp32 SGEMM 64x64 tile
template<bool RES, bool BF16OUT>
__device__ __forceinline__ void gemm_body(const float* __restrict__ A, const float* __restrict__ B,
                                          const float* __restrict__ bias, const float* __restrict__ res,
                                          void* __restrict__ Cv, int M, int Nc, int K){
  __shared__ float As[16][72];
  __shared__ float Bs[16][72];
  const int tid  = threadIdx.x;
  const int m0   = blockIdx.x*64, n0 = blockIdx.y*64;
  const int tx   = tid & 15, ty = tid >> 4;
  const int arow = tid >> 2, akq = tid & 3;
  const int brow = tid >> 4, bnq = tid & 15;
  float acc[4][4] = {};
  for(int k0 = 0; k0 < K; k0 += 16){
    __syncthreads();
    float4 av = *reinterpret_cast<const float4*>(A + (m0 + arow)*K + k0 + akq*4);
    As[akq*4+0][arow] = av.x; As[akq*4+1][arow] = av.y;
    As[akq*4+2][arow] = av.z; As[akq*4+3][arow] = av.w;
    float4 bv = *reinterpret_cast<const float4*>(B + (k0 + brow)*Nc + n0 + bnq*4);
    *reinterpret_cast<float4*>(&Bs[brow][bnq*4]) = bv;
    __syncthreads();
    #pragma unroll
    for(int kk = 0; kk < 16; ++kk){
      float4 a4 = *reinterpret_cast<const float4*>(&As[kk][ty*4]);
      float4 b4 = *reinterpret_cast<const float4*>(&Bs[kk][tx*4]);
      float a_[4] = {a4.x, a4.y, a4.z, a4.w};
      float b_[4] = {b4.x, b4.y, b4.z, b4.w};
      #pragma unroll
      for(int i=0;i<4;i++)
        #pragma unroll
        for(int j=0;j<4;j++)
          acc[i][j] = fmaf(a_[i], b_[j], acc[i][j]);
    }
  }
  #pragma unroll
  for(int i=0;i<4;i++){
    int r = m0 + ty*4 + i;
    int c = n0 + tx*4;
    float4 bi = *reinterpret_cast<const float4*>(bias + c);
    float o0 = acc[i][0] + bi.x, o1 = acc[i][1] + bi.y;
    float o2 = acc[i][2] + bi.z, o3 = acc[i][3] + bi.w;
    if(RES){
      float4 rv = *reinterpret_cast<const float4*>(res + r*Nc + c);
      o0 += rv.x; o1 += rv.y; o2 += rv.z; o3 += rv.w;
    }
    if(BF16OUT){
      u16x4 u; u.x = f2bf(o0); u.y = f2bf(o1); u.z = f2bf(o2); u.w = f2bf(o3);
      *reinterpret_cast<u16x4*>((u16*)Cv + (size_t)r*Nc + c) = u;
    }else{
      *reinterpret_cast<float4*>((float*)Cv + (size_t)r*Nc + c) = make_float4(o0,o1,o2,o3);
    }
  }
}

template<bool RES>
__global__ __launch_bounds__(256) void k_gemm(const float* __restrict__ A, const float* __restrict__ B,
                                              const float* __restrict__ bias, const float* __restrict__ res,
                                              float* __restrict__ C, int M, int Nc, int K){
  gemm_body<RES,false>(A, B, bias, res, C, M, Nc, K);
}

// grid.z = which*4 + head (0=q 1=k 2=v) — bf16 row-major output
__global__ __launch_bounds__(256) void k_qkv(const float* __restrict__ xln,
    const float* __restrict__ Wq, const float* __restrict__ Wk, const float* __restrict__ Wv,
    const float* __restrict__ bq, const float* __restrict__ bk, const float* __restrict__ bv,
    u16* __restrict__ q, u16* __restrict__ k, u16* __restrict__ v, int l){
  const int z = blockIdx.z, which = z >> 2, head = z & 3;
  const float* W; const float* bb; u16* out;
  if(which == 0){ W = Wq; bb = bq; out = q; }
  else if(which == 1){ W = Wk; bb = bk; out = k; }
  else { W = Wv; bb = bv; out = v; }
  W  += (l*H + head)*D*D;
  bb += (l*H + head)*D;
  out += (size_t)head*(N*D);
  gemm_body<false,true>(xln, W, bb, nullptr, out, N, D, D);
}

// ---------------------------------------------------------------- V transpose: [h][n][d] -> [h][d][n]
__global__ __launch_bounds__(256) void k_vt(const u16* __restrict__ vb, u16* __restrict__ vT){
  __shared__ u16 t[32][33];
  const int n0 = blockIdx.x*32, d0 = blockIdx.y*32, head = blockIdx.z;
  const int tid = threadIdx.x;
  #pragma unroll
  for(int i=0;i<4;i++){
    int idx = tid + i*256, r = idx >> 5, c = idx & 31;
    t[r][c] = vb[((size_t)head*N + n0 + r)*D + d0 + c];
  }
  __syncthreads();
  #pragma unroll
  for(int i=0;i<4;i++){
    int idx = tid + i*256, r = idx >> 5, c = idx & 31;
    vT[((size_t)head*D + d0 + r)*N + n0 + c] = t[c][r];
  }
}

// ---------------------------------------------------------------- MFMA flash attention
// 1 wave per block; grid (N/16, H, SPLIT). Each wave: 16 q-rows, iterate its key half in
// 32-key tiles. QK^T: mfma(Qfrag, Kfrag) -> S[col=lane&15=key, row=(lane>>4)*4+reg=q].
// P reshaped via small LDS to A-fragment layout; PV: mfma(Pfrag, VTfrag).
__global__ __launch_bounds__(64) void k_attn(const u16* __restrict__ q, const u16* __restrict__ k,
                     const u16* __restrict__ vT, const u16* __restrict__ biasm,
                     float* __restrict__ opart, float* __restrict__ mpart, float* __restrict__ lpart){
  const int qt = blockIdx.x, head = blockIdx.y, sp = blockIdx.z;
  const int lane = threadIdx.x;
  const int g4 = lane >> 4, l16 = lane & 15;
  const int r0 = qt*16;
  __shared__ u16 P[2][16][24];                     // [k-half][q-row][16 keys + 8 pad]

  // Q fragments: row = l16, k-chunk c: cols c*32 + g4*8 .. +8
  const u16* qbase = q + ((size_t)head*N + r0)*D;
  short8 qf[4];
  #pragma unroll
  for(int c=0;c<4;c++)
    qf[c] = *reinterpret_cast<const short8*>(qbase + l16*D + c*32 + g4*8);

  f32x4 o[8];
  #pragma unroll
  for(int dt=0;dt<8;dt++) o[dt] = (f32x4){0.f,0.f,0.f,0.f};
  f32x4 m = (f32x4){-INFINITY,-INFINITY,-INFINITY,-INFINITY};
  f32x4 lsum = (f32x4){0.f,0.f,0.f,0.f};

  const u16* bbase = biasm + (size_t)(r0 + g4*4)*N + l16;
  const int kv0 = sp*(N/SPLIT), kv1 = kv0 + N/SPLIT;

  for(int j0 = kv0; j0 < kv1; j0 += 32){
    // ---- QK^T for two 16-key tiles
    f32x4 sA = (f32x4){0.f,0.f,0.f,0.f}, sB = sA;
    const u16* kbA = k + ((size_t)head*N + j0)*D + l16*D + g4*8;
    #pragma unroll
    for(int c=0;c<4;c++){
      short8 kfA = *reinterpret_cast<const short8*>(kbA + c*32);
      short8 kfB = *reinterpret_cast<const short8*>(kbA + 16*D + c*32);
      sA = __builtin_amdgcn_mfma_f32_16x16x32_bf16(qf[c], kfA, sA, 0, 0, 0);
      sB = __builtin_amdgcn_mfma_f32_16x16x32_bf16(qf[c], kfB, sB, 0, 0, 0);
    }
    // ---- scale + bias (rows differ per reg!)
    #pragma unroll
    for(int rg=0;rg<4;rg++){
      sA[rg] = fmaf(sA[rg], SCALE, bf2f(bbase[(size_t)rg*N + j0]));
      sB[rg] = fmaf(sB[rg], SCALE, bf2f(bbase[(size_t)rg*N + j0 + 16]));
    }
    // ---- online softmax (per-row = per-reg, reduce across the 16 key-lanes)
    f32x4 t;
    #pragma unroll
    for(int rg=0;rg<4;rg++) t[rg] = fmaxf(sA[rg], sB[rg]);
    #pragma unroll
    for(int off=1; off<16; off<<=1){
      #pragma unroll
      for(int rg=0;rg<4;rg++) t[rg] = fmaxf(t[rg], __shfl_xor(t[rg], off));
    }
    f32x4 mnew, corr, pA, pB, psum;
    #pragma unroll
    for(int rg=0;rg<4;rg++){
      mnew[rg] = fmaxf(m[rg], t[rg]);
      corr[rg] = __expf(m[rg] - mnew[rg]);
      pA[rg]   = __expf(sA[rg] - mnew[rg]);
      pB[rg]   = __expf(sB[rg] - mnew[rg]);
      psum[rg] = pA[rg] + pB[rg];
    }
    #pragma unroll
    for(int off=1; off<16; off<<=1){
      #pragma unroll
      for(int rg=0;rg<4;rg++) psum[rg] += __shfl_xor(psum[rg], off);
    }
    #pragma unroll
    for(int rg=0;rg<4;rg++){
      lsum[rg] = fmaf(lsum[rg], corr[rg], psum[rg]);
      m[rg] = mnew[rg];
    }
    #pragma unroll
    for(int dt=0;dt<8;dt++) o[dt] *= corr;
    // ---- P -> LDS (bf16), reshaped for A-operand
    #pragma unroll
    for(int rg=0;rg<4;rg++){
      P[0][g4*4+rg][l16] = f2bf(pA[rg]);
      P[1][g4*4+rg][l16] = f2bf(pB[rg]);
    }
    // same-wave LDS write->read: DS pipe is in-order per wave, no barrier needed
    short8 pf = *reinterpret_cast<const short8*>(&P[g4>>1][l16][(g4&1)*8]);
    // ---- PV: B = vT rows (d), contiguous keys
    const u16* vb = vT + (size_t)head*D*N + (size_t)l16*N + j0 + g4*8;
    #pragma unroll
    for(int dt=0;dt<8;dt++){
      short8 vf = *reinterpret_cast<const short8*>(vb + (size_t)dt*16*N);
      o[dt] = __builtin_amdgcn_mfma_f32_16x16x32_bf16(pf, vf, o[dt], 0, 0, 0);
    }
  }

  // ---- store partials (unnormalized O, m, l)
  float* ob = opart + ((size_t)((sp*H + head)*N) + r0)*D;
  #pragma unroll
  for(int dt=0;dt<8;dt++){
    #pragma unroll
    for(int rg=0;rg<4;rg++)
      ob[(size_t)(g4*4+rg)*D + dt*16 + l16] = o[dt][rg];
  }
  if(l16 == 0){
    #pragma unroll
    for(int rg=0;rg<4;rg++){
      mpart[(size_t)(sp*H + head)*N + r0 + g4*4 + rg] = m[rg];
      lpart[(size_t)(sp*H + head)*N + r0 + g4*4 + rg] = lsum[rg];
    }
  }
}

// ---------------------------------------------------------------- split-K combine
__global__ __launch_bounds__(256) void k_comb(const float* __restrict__ opart,
                      const float* __restrict__ mpart, const float* __restrict__ lpart,
                      const float* __restrict__ mask, float* __restrict__ ocat){
  int idx = blockIdx.x*256 + threadIdx.x;          // < H*N*D
  int d = idx & (D-1);
  int r = (idx >> 7) % N;
  int h = idx / (N*D);
  size_t p0 = (size_t)(0*H + h)*N + r;
  size_t p1 = (size_t)(1*H + h)*N + r;
  float m0 = mpart[p0], m1 = mpart[p1];
  float M  = fmaxf(m0, m1);
  float w0 = __expf(m0 - M), w1 = __expf(m1 - M);
  float denom = lpart[p0]*w0 + lpart[p1]*w1;
  float val = opart[p0*D + d]*w0 + opart[p1*D + d]*w1;
  ocat[(size_t)r*(H*D) + h*D + d] = val * (mask[r] / denom);
}

// ---------------------------------------------------------------- launch
extern "C" void kernel_launch(void* const* d_in, const int* in_sizes, int n_in,
                              void* d_out, int out_size, void* d_ws, size_t ws_size,
                              hipStream_t stream){
  const float* x      = (const float*)d_in[0];
  const int*   ei     = (const int*)  d_in[1];
  const int*   spl    = (const int*)  d_in[2];
  const float* ef     = (const float*)d_in[3];
  const float* nodeW  = (const float*)d_in[4];
  const float* nodeb  = (const float*)d_in[5];
  const float* degemb = (const float*)d_in[6];
  const float* spe    = (const float*)d_in[7];
  const float* eW     = (const float*)d_in[8];
  const float* eb     = (const float*)d_in[9];
  const float* ln1g   = (const float*)d_in[10];
  const float* ln1b   = (const float*)d_in[11];
  const float* Wq     = (const float*)d_in[12];
  const float* bq     = (const float*)d_in[13];
  const float* Wk     = (const float*)d_in[14];
  const float* bk     = (const float*)d_in[15];
  const float* Wv     = (const float*)d_in[16];
  const float* bv     = (const float*)d_in[17];
  const float* Wo     = (const float*)d_in[18];
  const float* bo     = (const float*)d_in[19];
  const float* ln2g   = (const float*)d_in[20];
  const float* ln2b   = (const float*)d_in[21];
  const float* ffW    = (const float*)d_in[22];
  const float* ffb    = (const float*)d_in[23];
  const float* outW   = (const float*)d_in[24];
  const float* outb   = (const float*)d_in[25];

  float* ws   = (float*)d_ws;
  int*   deg  = (int*)ws;                       // N ints (4096-float slot)
  float* mask = ws + 4096;                      // N (4096-float slot)
  float* h    = ws + 8192;                      // N*D
  float* xln  = h    + N*D;
  float* xout = xln  + N*D;
  float* ocat = xout + N*D;                     // N*H*D fp32
  u16*   qb   = (u16*)(ocat + N*H*D);           // H*N*D bf16 each
  u16*   kb   = qb + (size_t)H*N*D;
  u16*   vb   = kb + (size_t)H*N*D;
  u16*   vT   = vb + (size_t)H*N*D;
  u16*   biasm= vT + (size_t)H*N*D;             // N*N bf16
  float* opart= (float*)(biasm + (size_t)N*N);  // SPLIT*H*N*D
  float* mpart= opart + (size_t)SPLIT*H*N*D;    // SPLIT*H*N
  float* lpart= mpart + (size_t)SPLIT*H*N;      // SPLIT*H*N
  // total ≈ 55.4 MB

  k_zero_deg<<<(N+255)/256, 256, 0, stream>>>(deg);
  k_deg<<<(E+255)/256, 256, 0, stream>>>(ei, deg);
  k_h0<<<N, 64, 0, stream>>>(x, nodeW, nodeb, degemb, deg, mask, h);
  k_bias<<<(N*N)/256, 256, 0, stream>>>(spl, ef, spe, eW, eb, mask, biasm);

  for(int l = 0; l < 2; ++l){
    k_ln<<<N/4, 256, 0, stream>>>(h, ln1g + l*D, ln1b + l*D, xln);
    k_qkv<<<dim3(N/64, D/64, 12), 256, 0, stream>>>(xln, Wq, Wk, Wv, bq, bk, bv, qb, kb, vb, l);
    k_vt<<<dim3(N/32, D/32, H), 256, 0, stream>>>(vb, vT);
    k_attn<<<dim3(N/16, H, SPLIT), 64, 0, stream>>>(qb, kb, vT, biasm, opart, mpart, lpart);
    k_comb<<<(H*N*D)/256, 256, 0, stream>>>(opart, mpart, lpart, mask, ocat);
    k_gemm<true><<<dim3(N/64, D/64), 256, 0, stream>>>(ocat, Wo + l*(H*D*D), bo + l*D, h, xout, N, D, H*D);
    k_ln<<<N/4, 256, 0, stream>>>(xout, ln2g + l*D, ln2b + l*D, xln);
    k_gemm<true><<<dim3(N/64, D/64), 256, 0, stream>>>(xln, ffW + l*D*D, ffb + l*D, xout, h, N, D, D);
  }
  k_gemm<false><<<dim3(N/64, D/64), 256, 0, stream>>>(h, outW, outb, nullptr, (float*)d_out, N, D, D);
}

// Round 3
// 504.055 us; speedup vs baseline: 3.2743x; 1.0033x over previous
//
#include <hip/hip_runtime.h>
#include <math.h>

static constexpr int N   = 3072;
static constexpr int DIN = 64;
static constexpr int D   = 128;
static constexpr int H   = 4;
static constexpr int E   = 49152;
#define NEGV  (-4294967295.0f)
#define SCALE (0.08838834764831845f)   // 1/sqrt(128)

typedef unsigned short u16;
typedef __attribute__((ext_vector_type(8))) short short8;
typedef __attribute__((ext_vector_type(4))) float f32x4;
typedef __attribute__((ext_vector_type(4))) unsigned short u16x4;

__device__ __forceinline__ u16 f2bf(float f){           // RNE float->bf16
  unsigned int u = __float_as_uint(f);
  u += 0x7fff + ((u >> 16) & 1);
  return (u16)(u >> 16);
}
__device__ __forceinline__ float bf2f(u16 u){
  return __uint_as_float(((unsigned int)u) << 16);
}

// ---------------------------------------------------------------- deg / h0
__global__ void k_zero_deg(int* __restrict__ deg){
  int i = blockIdx.x*blockDim.x + threadIdx.x;
  if(i < N) deg[i] = 0;
}

__global__ void k_deg(const int* __restrict__ ei, int* __restrict__ deg){
  int e = blockIdx.x*blockDim.x + threadIdx.x;
  if(e < E) atomicAdd(&deg[ei[E + e]], 1);
}

__global__ void k_h0(const float* __restrict__ x, const float* __restrict__ nodeW,
                     const float* __restrict__ nodeb, const float* __restrict__ degemb,
                     const int* __restrict__ deg, float* __restrict__ mask,
                     float* __restrict__ h){
  const int i = blockIdx.x, t = threadIdx.x;
  float xv = x[i*DIN + t];
  float s = xv;
  #pragma unroll
  for(int o=32;o;o>>=1) s += __shfl_xor(s, o);
  if(t == 0) mask[i] = (s != 0.0f) ? 1.0f : 0.0f;
  __shared__ float xr[DIN];
  xr[t] = xv;
  __syncthreads();
  int dg = deg[i]; dg = dg > N-1 ? N-1 : dg;
  float a0 = nodeb[t]      + degemb[dg*D + t];
  float a1 = nodeb[t + 64] + degemb[dg*D + t + 64];
  #pragma unroll
  for(int u=0; u<DIN; ++u){
    float xu = xr[u];
    a0 = fmaf(xu, nodeW[u*D + t],      a0);
    a1 = fmaf(xu, nodeW[u*D + t + 64], a1);
  }
  h[i*D + t]      = a0;
  h[i*D + t + 64] = a1;
}

// ---------------------------------------------------------------- bias (masked, bf16)
__global__ void k_bias(const int* __restrict__ spl, const float* __restrict__ ef,
                       const float* __restrict__ spe, const float* __restrict__ eW,
                       const float* __restrict__ eb, const float* __restrict__ mask,
                       u16* __restrict__ biasm){
  int idx = blockIdx.x*blockDim.x + threadIdx.x;   // < N*N
  int i = idx / N, j = idx % N;
  float wm0 = (eW[0] + eW[1] + eW[2] + eW[3])  * 0.25f;
  float wm1 = (eW[4] + eW[5] + eW[6] + eW[7])  * 0.25f;
  float wm2 = (eW[8] + eW[9] + eW[10]+ eW[11]) * 0.25f;
  float wm3 = (eW[12]+ eW[13]+ eW[14]+ eW[15]) * 0.25f;
  float bm  = (eb[0] + eb[1] + eb[2] + eb[3])  * 0.25f;
  float4 e4 = reinterpret_cast<const float4*>(ef)[idx];
  float em = fmaf(e4.x, wm0, fmaf(e4.y, wm1, fmaf(e4.z, wm2, fmaf(e4.w, wm3, bm))));
  float b = spe[spl[idx]] + em;
  float mk = mask[i]*mask[j];
  biasm[idx] = f2bf((mk != 0.0f) ? b : NEGV);
}

// ---------------------------------------------------------------- layernorm
__global__ void k_ln(const float* __restrict__ in, const float* __restrict__ g,
                     const float* __restrict__ b, float* __restrict__ out){
  const int w = threadIdx.x >> 6, lane = threadIdx.x & 63;
  const int row = blockIdx.x*4 + w;
  const float* r = in + row*D;
  float v0 = r[lane], v1 = r[lane + 64];
  float s = v0 + v1, sq = v0*v0 + v1*v1;
  #pragma unroll
  for(int o=32;o;o>>=1){ s += __shfl_xor(s, o); sq += __shfl_xor(sq, o); }
  float mean = s*(1.0f/128.0f);
  float var  = sq*(1.0f/128.0f) - mean*mean;
  float inv  = rsqrtf(var + 1e-5f);
  out[row*D + lane]      = (v0 - mean)*inv*g[lane]      + b[lane];
  out[row*D + lane + 64] = (v1 - mean)*inv*g[lane + 64] + b[lane + 64];
}

// ---------------------------------------------------------------- fp32 SGEMM 64x64 tile
template<bool RES, bool BF16OUT>
__device__ __forceinline__ void gemm_body(const float* __restrict__ A, const float* __restrict__ B,
                                          const float* __restrict__ bias, const float* __restrict__ res,
                                          void* __restrict__ Cv, int M, int Nc, int K){
  __shared__ float As[16][72];
  __shared__ float Bs[16][72];
  const int tid  = threadIdx.x;
  const int m0   = blockIdx.x*64, n0 = blockIdx.y*64;
  const int tx   = tid & 15, ty = tid >> 4;
  const int arow = tid >> 2, akq = tid & 3;
  const int brow = tid >> 4, bnq = tid & 15;
  float acc[4][4] = {};
  for(int k0 = 0; k0 < K; k0 += 16){
    __syncthreads();
    float4 av = *reinterpret_cast<const float4*>(A + (m0 + arow)*K + k0 + akq*4);
    As[akq*4+0][arow] = av.x; As[akq*4+1][arow] = av.y;
    As[akq*4+2][arow] = av.z; As[akq*4+3][arow] = av.w;
    float4 bv = *reinterpret_cast<const float4*>(B + (k0 + brow)*Nc + n0 + bnq*4);
    *reinterpret_cast<float4*>(&Bs[brow][bnq*4]) = bv;
    __syncthreads();
    #pragma unroll
    for(int kk = 0; kk < 16; ++kk){
      float4 a4 = *reinterpret_cast<const float4*>(&As[kk][ty*4]);
      float4 b4 = *reinterpret_cast<const float4*>(&Bs[kk][tx*4]);
      float a_[4] = {a4.x, a4.y, a4.z, a4.w};
      float b_[4] = {b4.x, b4.y, b4.z, b4.w};
      #pragma unroll
      for(int i=0;i<4;i++)
        #pragma unroll
        for(int j=0;j<4;j++)
          acc[i][j] = fmaf(a_[i], b_[j], acc[i][j]);
    }
  }
  #pragma unroll
  for(int i=0;i<4;i++){
    int r = m0 + ty*4 + i;
    int c = n0 + tx*4;
    float4 bi = *reinterpret_cast<const float4*>(bias + c);
    float o0 = acc[i][0] + bi.x, o1 = acc[i][1] + bi.y;
    float o2 = acc[i][2] + bi.z, o3 = acc[i][3] + bi.w;
    if(RES){
      float4 rv = *reinterpret_cast<const float4*>(res + r*Nc + c);
      o0 += rv.x; o1 += rv.y; o2 += rv.z; o3 += rv.w;
    }
    if(BF16OUT){
      u16x4 u; u.x = f2bf(o0); u.y = f2bf(o1); u.z = f2bf(o2); u.w = f2bf(o3);
      *reinterpret_cast<u16x4*>((u16*)Cv + (size_t)r*Nc + c) = u;
    }else{
      *reinterpret_cast<float4*>((float*)Cv + (size_t)r*Nc + c) = make_float4(o0,o1,o2,o3);
    }
  }
}

template<bool RES>
__global__ __launch_bounds__(256) void k_gemm(const float* __restrict__ A, const float* __restrict__ B,
                                              const float* __restrict__ bias, const float* __restrict__ res,
                                              float* __restrict__ C, int M, int Nc, int K){
  gemm_body<RES,false>(A, B, bias, res, C, M, Nc, K);
}

// grid.z = which*4 + head (0=q 1=k 2=v) — bf16 row-major output
__global__ __launch_bounds__(256) void k_qkv(const float* __restrict__ xln,
    const float* __restrict__ Wq, const float* __restrict__ Wk, const float* __restrict__ Wv,
    const float* __restrict__ bq, const float* __restrict__ bk, const float* __restrict__ bv,
    u16* __restrict__ q, u16* __restrict__ k, u16* __restrict__ v, int l){
  const int z = blockIdx.z, which = z >> 2, head = z & 3;
  const float* W; const float* bb; u16* out;
  if(which == 0){ W = Wq; bb = bq; out = q; }
  else if(which == 1){ W = Wk; bb = bk; out = k; }
  else { W = Wv; bb = bv; out = v; }
  W  += (l*H + head)*D*D;
  bb += (l*H + head)*D;
  out += (size_t)head*(N*D);
  gemm_body<false,true>(xln, W, bb, nullptr, out, N, D, D);
}

// ---------------------------------------------------------------- V transpose: [h][n][d] -> [h][d][n]
__global__ __launch_bounds__(256) void k_vt(const u16* __restrict__ vb, u16* __restrict__ vT){
  __shared__ u16 t[32][33];
  const int n0 = blockIdx.x*32, d0 = blockIdx.y*32, head = blockIdx.z;
  const int tid = threadIdx.x;
  #pragma unroll
  for(int i=0;i<4;i++){
    int idx = tid + i*256, r = idx >> 5, c = idx & 31;
    t[r][c] = vb[((size_t)head*N + n0 + r)*D + d0 + c];
  }
  __syncthreads();
  #pragma unroll
  for(int i=0;i<4;i++){
    int idx = tid + i*256, r = idx >> 5, c = idx & 31;
    vT[((size_t)head*D + d0 + r)*N + n0 + c] = t[c][r];
  }
}

// ---------------------------------------------------------------- MFMA flash attention
// 4 waves/block, 1 q-tile (16 rows) per wave; grid (N/64, H, SPLIT).
// QK^T: mfma(Qfrag, Kfrag) -> S[col=lane&15=key, row=(lane>>4)*4+reg=q].
// Defer-rescale (THR=8). P via per-wave LDS slice to A-fragment; PV: mfma(Pfrag, VTfrag).
__global__ __launch_bounds__(256) void k_attn(const u16* __restrict__ q, const u16* __restrict__ k,
                     const u16* __restrict__ vT, const u16* __restrict__ biasm,
                     float* __restrict__ opart, float* __restrict__ mpart, float* __restrict__ lpart,
                     int kvlen){
  const int w    = threadIdx.x >> 6;
  const int lane = threadIdx.x & 63;
  const int qt   = blockIdx.x*4 + w;
  const int head = blockIdx.y, sp = blockIdx.z;
  const int g4 = lane >> 4, l16 = lane & 15;
  const int r0 = qt*16;
  __shared__ u16 P[4][2][16][24];                  // per-wave slice

  const u16* qbase = q + ((size_t)head*N + r0)*D;
  short8 qf[4];
  #pragma unroll
  for(int c=0;c<4;c++)
    qf[c] = *reinterpret_cast<const short8*>(qbase + l16*D + c*32 + g4*8);

  f32x4 o[8];
  #pragma unroll
  for(int dt=0;dt<8;dt++) o[dt] = (f32x4){0.f,0.f,0.f,0.f};
  f32x4 m = (f32x4){-INFINITY,-INFINITY,-INFINITY,-INFINITY};
  f32x4 lsum = (f32x4){0.f,0.f,0.f,0.f};

  const u16* bbase = biasm + (size_t)(r0 + g4*4)*N + l16;
  const int kv0 = sp*kvlen, kv1 = kv0 + kvlen;

  for(int j0 = kv0; j0 < kv1; j0 += 32){
    // ---- QK^T for two 16-key tiles
    f32x4 sA = (f32x4){0.f,0.f,0.f,0.f}, sB = sA;
    const u16* kbA = k + ((size_t)head*N + j0)*D + l16*D + g4*8;
    __builtin_amdgcn_s_setprio(1);
    #pragma unroll
    for(int c=0;c<4;c++){
      short8 kfA = *reinterpret_cast<const short8*>(kbA + c*32);
      short8 kfB = *reinterpret_cast<const short8*>(kbA + 16*D + c*32);
      sA = __builtin_amdgcn_mfma_f32_16x16x32_bf16(qf[c], kfA, sA, 0, 0, 0);
      sB = __builtin_amdgcn_mfma_f32_16x16x32_bf16(qf[c], kfB, sB, 0, 0, 0);
    }
    __builtin_amdgcn_s_setprio(0);
    // ---- scale + bias (rows differ per reg)
    #pragma unroll
    for(int rg=0;rg<4;rg++){
      sA[rg] = fmaf(sA[rg], SCALE, bf2f(bbase[(size_t)rg*N + j0]));
      sB[rg] = fmaf(sB[rg], SCALE, bf2f(bbase[(size_t)rg*N + j0 + 16]));
    }
    // ---- row max (reduce across the 16 key-lanes)
    f32x4 t;
    #pragma unroll
    for(int rg=0;rg<4;rg++) t[rg] = fmaxf(sA[rg], sB[rg]);
    #pragma unroll
    for(int off=1; off<16; off<<=1){
      #pragma unroll
      for(int rg=0;rg<4;rg++) t[rg] = fmaxf(t[rg], __shfl_xor(t[rg], off));
    }
    // ---- defer-rescale (THR=8): only pay corr/O-rescale when max actually grows
    float dm = fmaxf(fmaxf(t[0]-m[0], t[1]-m[1]), fmaxf(t[2]-m[2], t[3]-m[3]));
    if(!__all(dm <= 8.0f)){
      f32x4 mnew, corr;
      #pragma unroll
      for(int rg=0;rg<4;rg++){
        mnew[rg] = fmaxf(m[rg], t[rg]);
        corr[rg] = __expf(m[rg] - mnew[rg]);
      }
      lsum *= corr;
      #pragma unroll
      for(int dt=0;dt<8;dt++) o[dt] *= corr;
      m = mnew;
    }
    // ---- P = exp(S - m), bounded by e^8
    f32x4 pA, pB, psum;
    #pragma unroll
    for(int rg=0;rg<4;rg++){
      pA[rg]   = __expf(sA[rg] - m[rg]);
      pB[rg]   = __expf(sB[rg] - m[rg]);
      psum[rg] = pA[rg] + pB[rg];
    }
    #pragma unroll
    for(int off=1; off<16; off<<=1){
      #pragma unroll
      for(int rg=0;rg<4;rg++) psum[rg] += __shfl_xor(psum[rg], off);
    }
    lsum += psum;
    // ---- P -> LDS (bf16), reshaped for A-operand
    #pragma unroll
    for(int rg=0;rg<4;rg++){
      P[w][0][g4*4+rg][l16] = f2bf(pA[rg]);
      P[w][1][g4*4+rg][l16] = f2bf(pB[rg]);
    }
    // same-wave LDS write->read: DS pipe in-order per wave, no barrier needed
    short8 pf = *reinterpret_cast<const short8*>(&P[w][g4>>1][l16][(g4&1)*8]);
    // ---- PV: B = vT rows (d), contiguous keys
    const u16* vb = vT + (size_t)head*D*N + (size_t)l16*N + j0 + g4*8;
    __builtin_amdgcn_s_setprio(1);
    #pragma unroll
    for(int dt=0;dt<8;dt++){
      short8 vf = *reinterpret_cast<const short8*>(vb + (size_t)dt*16*N);
      o[dt] = __builtin_amdgcn_mfma_f32_16x16x32_bf16(pf, vf, o[dt], 0, 0, 0);
    }
    __builtin_amdgcn_s_setprio(0);
  }

  // ---- store partials (unnormalized O, m, l)
  float* ob = opart + ((size_t)((sp*H + head)*N) + r0)*D;
  #pragma unroll
  for(int dt=0;dt<8;dt++){
    #pragma unroll
    for(int rg=0;rg<4;rg++)
      ob[(size_t)(g4*4+rg)*D + dt*16 + l16] = o[dt][rg];
  }
  if(l16 == 0){
    #pragma unroll
    for(int rg=0;rg<4;rg++){
      mpart[(size_t)(sp*H + head)*N + r0 + g4*4 + rg] = m[rg];
      lpart[(size_t)(sp*H + head)*N + r0 + g4*4 + rg] = lsum[rg];
    }
  }
}

// ---------------------------------------------------------------- split-K combine
template<int S>
__global__ __launch_bounds__(256) void k_comb(const float* __restrict__ opart,
                      const float* __restrict__ mpart, const float* __restrict__ lpart,
                      const float* __restrict__ mask, float* __restrict__ ocat){
  int idx = blockIdx.x*256 + threadIdx.x;          // < H*N*D
  int d = idx & (D-1);
  int r = (idx >> 7) % N;
  int h = idx / (N*D);
  float mv[S], lv[S];
  float M = -INFINITY;
  #pragma unroll
  for(int s=0;s<S;s++){
    size_t p = (size_t)(s*H + h)*N + r;
    mv[s] = mpart[p]; lv[s] = lpart[p];
    M = fmaxf(M, mv[s]);
  }
  float denom = 0.f, val = 0.f;
  #pragma unroll
  for(int s=0;s<S;s++){
    size_t p = (size_t)(s*H + h)*N + r;
    float wgt = __expf(mv[s] - M);
    denom = fmaf(lv[s], wgt, denom);
    val   = fmaf(opart[p*D + d], wgt, val);
  }
  ocat[(size_t)r*(H*D) + h*D + d] = val * (mask[r] / denom);
}

// ---------------------------------------------------------------- launch
extern "C" void kernel_launch(void* const* d_in, const int* in_sizes, int n_in,
                              void* d_out, int out_size, void* d_ws, size_t ws_size,
                              hipStream_t stream){
  const float* x      = (const float*)d_in[0];
  const int*   ei     = (const int*)  d_in[1];
  const int*   spl    = (const int*)  d_in[2];
  const float* ef     = (const float*)d_in[3];
  const float* nodeW  = (const float*)d_in[4];
  const float* nodeb  = (const float*)d_in[5];
  const float* degemb = (const float*)d_in[6];
  const float* spe    = (const float*)d_in[7];
  const float* eW     = (const float*)d_in[8];
  const float* eb     = (const float*)d_in[9];
  const float* ln1g   = (const float*)d_in[10];
  const float* ln1b   = (const float*)d_in[11];
  const float* Wq     = (const float*)d_in[12];
  const float* bq     = (const float*)d_in[13];
  const float* Wk     = (const float*)d_in[14];
  const float* bk     = (const float*)d_in[15];
  const float* Wv     = (const float*)d_in[16];
  const float* bv     = (const float*)d_in[17];
  const float* Wo     = (const float*)d_in[18];
  const float* bo     = (const float*)d_in[19];
  const float* ln2g   = (const float*)d_in[20];
  const float* ln2b   = (const float*)d_in[21];
  const float* ffW    = (const float*)d_in[22];
  const float* ffb    = (const float*)d_in[23];
  const float* outW   = (const float*)d_in[24];
  const float* outb   = (const float*)d_in[25];

  // pick SPLIT by available workspace (deterministic in ws_size)
  auto needed = [](int s)->size_t{
    size_t fl = 8192 + 3*(size_t)N*D + (size_t)N*H*D;          // fp32 elems
    size_t bf = 4*(size_t)H*N*D + (size_t)N*N;                 // bf16 elems
    size_t pf = (size_t)s*H*N*D + 2*(size_t)s*H*N;             // fp32 partials
    return fl*4 + bf*2 + pf*4;
  };
  int S = 2;
  if(needed(8) <= ws_size) S = 8;
  else if(needed(4) <= ws_size) S = 4;

  float* ws   = (float*)d_ws;
  int*   deg  = (int*)ws;                       // N ints (4096-float slot)
  float* mask = ws + 4096;                      // N (4096-float slot)
  float* h    = ws + 8192;                      // N*D
  float* xln  = h    + N*D;
  float* xout = xln  + N*D;
  float* ocat = xout + N*D;                     // N*H*D fp32
  u16*   qb   = (u16*)(ocat + N*H*D);           // H*N*D bf16 each
  u16*   kb   = qb + (size_t)H*N*D;
  u16*   vb   = kb + (size_t)H*N*D;
  u16*   vT   = vb + (size_t)H*N*D;
  u16*   biasm= vT + (size_t)H*N*D;             // N*N bf16
  float* opart= (float*)(biasm + (size_t)N*N);  // S*H*N*D
  float* mpart= opart + (size_t)S*H*N*D;        // S*H*N
  float* lpart= mpart + (size_t)S*H*N;          // S*H*N

  k_zero_deg<<<(N+255)/256, 256, 0, stream>>>(deg);
  k_deg<<<(E+255)/256, 256, 0, stream>>>(ei, deg);
  k_h0<<<N, 64, 0, stream>>>(x, nodeW, nodeb, degemb, deg, mask, h);
  k_bias<<<(N*N)/256, 256, 0, stream>>>(spl, ef, spe, eW, eb, mask, biasm);

  for(int l = 0; l < 2; ++l){
    k_ln<<<N/4, 256, 0, stream>>>(h, ln1g + l*D, ln1b + l*D, xln);
    k_qkv<<<dim3(N/64, D/64, 12), 256, 0, stream>>>(xln, Wq, Wk, Wv, bq, bk, bv, qb, kb, vb, l);
    k_vt<<<dim3(N/32, D/32, H), 256, 0, stream>>>(vb, vT);
    k_attn<<<dim3(N/64, H, S), 256, 0, stream>>>(qb, kb, vT, biasm, opart, mpart, lpart, N/S);
    if(S == 8)      k_comb<8><<<(H*N*D)/256, 256, 0, stream>>>(opart, mpart, lpart, mask, ocat);
    else if(S == 4) k_comb<4><<<(H*N*D)/256, 256, 0, stream>>>(opart, mpart, lpart, mask, ocat);
    else            k_comb<2><<<(H*N*D)/256, 256, 0, stream>>>(opart, mpart, lpart, mask, ocat);
    k_gemm<true><<<dim3(N/64, D/64), 256, 0, stream>>>(ocat, Wo + l*(H*D*D), bo + l*D, h, xout, N, D, H*D);
    k_ln<<<N/4, 256, 0, stream>>>(xout, ln2g + l*D, ln2b + l*D, xln);
    k_gemm<true><<<dim3(N/64, D/64), 256, 0, stream>>>(xln, ffW + l*D*D, ffb + l*D, xout, h, N, D, D);
  }
  k_gemm<false><<<dim3(N/64, D/64), 256, 0, stream>>>(h, outW, outb, nullptr, (float*)d_out, N, D, D);
}